// Round 5
// baseline (178.947 us; speedup 1.0000x reference)
//
#include <hip/hip_runtime.h>

#define B_ 4096
#define C_ 128
#define D_ 768
#define NT 256
#define NT2 512                 // k_select block
#define M_SEL 128               // max class size for fast select path (17 sigma)
#define P_SEL (M_SEL*(M_SEL-1)/2)   // 8128
#define SG_CAP 131072           // pair-buffer capacity (floats)
#define PAIR_BLOCKS 2048
#define NWAVE2 (NT2/64)

__device__ __forceinline__ float wave_red(float v){
#pragma unroll
  for (int o = 32; o > 0; o >>= 1) v += __shfl_down(v, o, 64);
  return v;
}
__device__ __forceinline__ float wave_min(float v){
#pragma unroll
  for (int o = 32; o > 0; o >>= 1) v = fminf(v, __shfl_down(v, o, 64));
  return v;
}
__device__ __forceinline__ float wave_max(float v){
#pragma unroll
  for (int o = 32; o > 0; o >>= 1) v = fmaxf(v, __shfl_down(v, o, 64));
  return v;
}
__device__ __forceinline__ float clamp1(float x){ return fminf(fmaxf(x, -1.f), 1.f); }
__device__ __forceinline__ unsigned rotl32(unsigned x, int r){ return (x << r) | (x >> (32 - r)); }

// jax.random.uniform(jax.random.key(1),(B,B)) element n: Threefry-2x32 key (0,1),
// counters split in halves. Bit-exact (verified round 1: absmax 0.0).
__device__ float rand_ij(unsigned n){
  const unsigned half = (unsigned)B_ * (unsigned)B_ / 2u;
  unsigned c0, c1; bool hi;
  if (n < half){ c0 = n; c1 = n + half; hi = false; }
  else         { c0 = n - half; c1 = n; hi = true; }
  const unsigned K0 = 0u, K1 = 1u, K2 = 0x1BD11BDBu;
  unsigned x0 = c0 + K0, x1 = c1 + K1;
#define TFR(r) { x0 += x1; x1 = rotl32(x1, (r)); x1 ^= x0; }
  TFR(13) TFR(15) TFR(26) TFR(6)  x0 += K1; x1 += K2 + 1u;
  TFR(17) TFR(29) TFR(16) TFR(24) x0 += K2; x1 += K0 + 2u;
  TFR(13) TFR(15) TFR(26) TFR(6)  x0 += K0; x1 += K1 + 3u;
  TFR(17) TFR(29) TFR(16) TFR(24) x0 += K1; x1 += K2 + 4u;
  TFR(13) TFR(15) TFR(26) TFR(6)  x0 += K2; x1 += K0 + 5u;
#undef TFR
  unsigned bits = hi ? x1 : x0;
  return __uint_as_float((bits >> 9) | 0x3F800000u) - 1.0f;
}

// p -> (a,b), a<b<m, row-major upper-tri. before(a) = a*(2m-1-a)/2.
__device__ __forceinline__ void decode_pair(int p, int m, int* a_, int* b_){
  float fm = (float)(2*m - 1);
  int a = (int)((fm - sqrtf(fm*fm - 8.0f*(float)p)) * 0.5f);
  a = max(0, min(a, m - 2));
  while (a > 0 && (a*(2*m - 1 - a))/2 > p) --a;
  while (((a + 1)*(2*m - 2 - a))/2 <= p) ++a;
  *a_ = a;
  *b_ = a + 1 + (p - (a*(2*m - 1 - a))/2);
}

// ---- slow-path helpers (unreachable on this dataset; correctness insurance) ----
__device__ float pair_dot_g(const float* feat, const float* rnorm, const int* mem, int a, int b){
  const float* ra = feat + (size_t)mem[a] * D_;
  const float* rb = feat + (size_t)mem[b] * D_;
  float s = 0.f;
  for (int k = 0; k < D_; ++k) s = fmaf(ra[k], rb[k], s);
  return s * rnorm[mem[a]] * rnorm[mem[b]];
}

// ---- kernel 1: norms + raw EC dots; one extra block does hist/scan/scatter ----
__global__ __launch_bounds__(NT) void k_norms(
    const float* __restrict__ feat, const float* __restrict__ cent,
    const int* __restrict__ labels, float* __restrict__ rnorm,
    float* __restrict__ cnorm, float* __restrict__ rawEC,
    int* __restrict__ cnt, int* __restrict__ offs, int* __restrict__ poffs,
    int* __restrict__ TP, int* __restrict__ members,
    float* __restrict__ acc2, int* __restrict__ done)
{
  const int blk = blockIdx.x;
  const int tid = threadIdx.x;

  if (blk == B_ + C_){
    // binning block: histogram -> exclusive scans (rows + pairs) -> scatter
    __shared__ int hist[C_], curs[C_], soffs[C_];
    if (tid < C_){ hist[tid] = 0; curs[tid] = 0; }
    if (tid == 0){ acc2[0] = 0.f; acc2[1] = 0.f; *done = 0; }
    __syncthreads();
    for (int i = tid; i < B_; i += NT) atomicAdd(&hist[labels[i]], 1);
    __syncthreads();
    if (tid == 0){
      int acc = 0, pacc = 0;
      for (int c = 0; c < C_; ++c){
        int m = hist[c];
        cnt[c] = m; offs[c] = acc; soffs[c] = acc; poffs[c] = pacc;
        acc += m; pacc += m * (m - 1) / 2;
      }
      poffs[C_] = pacc; *TP = pacc;
    }
    __syncthreads();
    for (int i = tid; i < B_; i += NT){
      int c = labels[i];
      int pos = atomicAdd(&curs[c], 1);
      members[soffs[c] + pos] = i;
    }
    return;
  }

  const bool isF = (blk < B_);
  const int row = isF ? blk : blk - B_;
  const float* src = isF ? (feat + (size_t)row * D_) : (cent + (size_t)row * D_);
  const float* cc  = isF ? (cent + (size_t)labels[row] * D_) : nullptr;

  float ss = 0.f, sd = 0.f;
  for (int k = tid; k < D_; k += NT){
    float v = src[k];
    ss = fmaf(v, v, ss);
    if (isF) sd = fmaf(v, cc[k], sd);
  }
  ss = wave_red(ss); sd = wave_red(sd);
  __shared__ float sb[4], sb2[4];
  int wid = tid >> 6, lane = tid & 63;
  if (lane == 0){ sb[wid] = ss; sb2[wid] = sd; }
  __syncthreads();
  if (tid == 0){
    float t = sb[0] + sb[1] + sb[2] + sb[3];
    float rn = 1.f / fmaxf(sqrtf(t), 1e-12f);
    if (isF){ rnorm[row] = rn; rawEC[row] = sb2[0] + sb2[1] + sb2[2] + sb2[3]; }
    else cnorm[row] = rn;
  }
}

// ---- kernel 2: one wave per pair -> S values ----
__global__ __launch_bounds__(NT) void k_pairs(
    const float* __restrict__ feat, const float* __restrict__ rnorm,
    const int* __restrict__ cnt, const int* __restrict__ offs,
    const int* __restrict__ poffs, const int* __restrict__ TP,
    const int* __restrict__ members, float* __restrict__ Sg, int cap)
{
  __shared__ int spoffs[C_ + 1], scnt[C_], soffs[C_];
  const int tid = threadIdx.x;
  if (tid < C_){ scnt[tid] = cnt[tid]; soffs[tid] = offs[tid]; }
  if (tid <= C_) spoffs[tid] = poffs[tid];
  __syncthreads();

  const int tp = min(TP[0], cap);
  const int lane = tid & 63;
  const int nw = (gridDim.x * NT) >> 6;
  int w = (blockIdx.x * NT + tid) >> 6;

  for (int p = w; p < tp; p += nw){
    int lo = 0, hi = C_;
    while (hi - lo > 1){ int mid = (lo + hi) >> 1; if (spoffs[mid] <= p) lo = mid; else hi = mid; }
    const int c = lo;
    const int pl = p - spoffs[c];
    const int m = scnt[c];
    int a, b; decode_pair(pl, m, &a, &b);
    const int ga = members[soffs[c] + a];
    const int gb = members[soffs[c] + b];
    const float4* ra = (const float4*)(feat + (size_t)ga * D_);
    const float4* rb = (const float4*)(feat + (size_t)gb * D_);
    float s = 0.f;
#pragma unroll
    for (int k = 0; k < D_ / 256; ++k){           // 3 iters: lane + 64k < 192
      float4 x = ra[lane + 64 * k];
      float4 y = rb[lane + 64 * k];
      s = fmaf(x.x, y.x, s); s = fmaf(x.y, y.y, s);
      s = fmaf(x.z, y.z, s); s = fmaf(x.w, y.w, s);
    }
    s = wave_red(s);
    if (lane == 0) Sg[p] = s * rnorm[ga] * rnorm[gb];
  }
}

// ---- kernel 3: per-class median (ballot rank-select, atomic-free) + loss ----
__global__ __launch_bounds__(NT2) void k_select(
    const float* __restrict__ feat, const float* __restrict__ rnorm,
    const float* __restrict__ cnorm, const float* __restrict__ rawEC,
    const int* __restrict__ cnt, const int* __restrict__ offs,
    const int* __restrict__ poffs, const int* __restrict__ members,
    const float* __restrict__ Sg, int cap,
    float* __restrict__ acc2, int* __restrict__ done, float* __restrict__ out)
{
  const int c = blockIdx.x;
  const int m = cnt[c];
  const int tid = threadIdx.x;
  const int wid = tid >> 6, lane = tid & 63;

  __shared__ __align__(16) float Sl[P_SEL];   // raw S per pair
  __shared__ __align__(16) float Pd[P_SEL];   // pd = 1 - clip(S)
  __shared__ int   wcnt[NWAVE2 * 64];         // per-wave 64-bucket counts
  __shared__ float mnb[NWAVE2], mxb[NWAVE2];
  __shared__ float ec_s[M_SEL];
  __shared__ int   gid_s[M_SEL];
  __shared__ float range_sh[2];               // pdmin, scale
  __shared__ int   selb_sh;
  __shared__ float thr_sh;
  __shared__ float redbuf[16];

  float lloss = 0.f, lw = 0.f;

  if (m >= 2){
    const int base = offs[c];
    const int pbase = poffs[c];
    const int P = m * (m - 1) / 2;
    const int k0 = (P - 1) >> 1;
    const float wc = (float)m;
    const float cn = cnorm[c];
    const bool fast = (m <= M_SEL) && (pbase + P <= cap);

    if (fast){
      // pass 0: load S, compute pd, track block min/max of pd
      float pmn = 1e30f, pmx = -1e30f;
      for (int p = tid; p < P; p += NT2){
        float s = Sg[pbase + p];
        float pd = 1.f - clamp1(s);
        Sl[p] = s;
        Pd[p] = pd;
        pmn = fminf(pmn, pd); pmx = fmaxf(pmx, pd);
      }
      if (tid < m){
        int g = members[base + tid];
        gid_s[tid] = g;
        ec_s[tid] = rawEC[g] * rnorm[g] * cn;
      }
      pmn = wave_min(pmn); pmx = wave_max(pmx);
      if (lane == 0){ mnb[wid] = pmn; mxb[wid] = pmx; }
      __syncthreads();
      if (tid == 0){
        float mn = mnb[0], mx = mxb[0];
#pragma unroll
        for (int i = 1; i < NWAVE2; ++i){ mn = fminf(mn, mnb[i]); mx = fmaxf(mx, mxb[i]); }
        range_sh[0] = mn;
        range_sh[1] = 64.f / (mx - mn + 1e-30f);
      }
      __syncthreads();
      const float pdmin = range_sh[0], scale = range_sh[1];

      // pass 1: per-wave 64-bucket histogram via ballot (no LDS atomics)
      int cl = 0;  // this lane's count for bucket == lane
      const int nch = (P + NT2 - 1) / NT2;
      for (int t = 0; t < nch; ++t){
        int p = tid + t * NT2;
        int bkt = -1;
        if (p < P) bkt = min(63, (int)((Pd[p] - pdmin) * scale));
#pragma unroll
        for (int k = 0; k < 64; ++k){
          unsigned long long msk = __ballot(bkt == k);
          if (lane == k) cl += __popcll(msk);
        }
      }
      wcnt[wid * 64 + lane] = cl;
      __syncthreads();
      if (tid < 64){
        int tot = 0;
#pragma unroll
        for (int w = 0; w < NWAVE2; ++w) tot += wcnt[w * 64 + tid];
        int inc = tot;
#pragma unroll
        for (int o = 1; o < 64; o <<= 1){
          int v = __shfl_up(inc, o, 64);
          if (tid >= o) inc += v;
        }
        int excl = inc - tot;
        if (excl <= k0 && k0 < inc) selb_sh = tid;
      }
      __syncthreads();

      // pass 2: exact lt/eq recount, candidates-in-selected-bucket only
      const int bsel = selb_sh;
      const float4* Pd4 = (const float4*)Pd;
      const int nq4 = P >> 2;
      for (int p = tid; p < P; p += NT2){
        const float pdp = Pd[p];
        if (min(63, (int)((pdp - pdmin) * scale)) == bsel){
          int lt = 0, eq = 0;
#pragma unroll 4
          for (int q4 = 0; q4 < nq4; ++q4){
            float4 v = Pd4[q4];
            lt += (v.x < pdp) + (v.y < pdp) + (v.z < pdp) + (v.w < pdp);
            eq += (v.x == pdp) + (v.y == pdp) + (v.z == pdp) + (v.w == pdp);
          }
          for (int q = nq4 << 2; q < P; ++q){
            float pdq = Pd[q];
            lt += (pdq < pdp); eq += (pdq == pdp);
          }
          if (lt <= k0 && k0 < lt + eq) thr_sh = pdp;
        }
      }
      __syncthreads();
      const float thr = thr_sh;
      for (int p = tid; p < P; p += NT2){
        float S = Sl[p];
        float pd = Pd[p];
        if (pd > thr){
          int a, b; decode_pair(p, m, &a, &b);
          int ga = gid_s[a], gb = gid_s[b];
          float ea = ec_s[a], eb = ec_s[b];
          int i, j; float eci, ecj;
          if (ga < gb){ i = ga; j = gb; eci = ea; ecj = eb; }
          else        { i = gb; j = ga; eci = eb; ecj = ea; }
          float r = rand_ij((unsigned)i * (unsigned)B_ + (unsigned)j);
          float omr = 1.f - r;
          float n2 = r * r + omr * omr + 2.f * r * omr * S;   // raw S
          float nrm = fmaxf(sqrtf(fmaxf(n2, 0.f)), 1e-12f);
          float dt = clamp1((r * eci + omr * ecj) / nrm);
          lloss += wc * (1.f - dt);
          lw += wc;
        }
      }
    } else {
      // correctness-only fallback (m > M_SEL or pair-buffer overflow)
      for (int p = tid; p < P; p += NT2){
        int a, b; decode_pair(p, m, &a, &b);
        float Sp = pair_dot_g(feat, rnorm, members + base, a, b);
        float pdp = 1.f - clamp1(Sp);
        int lt = 0, eq = 0;
        for (int q = 0; q < P; ++q){
          int a2, b2; decode_pair(q, m, &a2, &b2);
          float pdq = 1.f - clamp1(pair_dot_g(feat, rnorm, members + base, a2, b2));
          lt += (pdq < pdp); eq += (pdq == pdp);
        }
        if (lt <= k0 && k0 < lt + eq) thr_sh = pdp;
      }
      __syncthreads();
      const float thr = thr_sh;
      for (int p = tid; p < P; p += NT2){
        int a, b; decode_pair(p, m, &a, &b);
        float S = pair_dot_g(feat, rnorm, members + base, a, b);
        float pd = 1.f - clamp1(S);
        if (pd > thr){
          int ga = members[base + a], gb = members[base + b];
          if (ga > gb){ int t2 = ga; ga = gb; gb = t2; }
          float eci = rawEC[ga] * rnorm[ga] * cn;
          float ecj = rawEC[gb] * rnorm[gb] * cn;
          float r = rand_ij((unsigned)ga * (unsigned)B_ + (unsigned)gb);
          float omr = 1.f - r;
          float n2 = r * r + omr * omr + 2.f * r * omr * S;
          float nrm = fmaxf(sqrtf(fmaxf(n2, 0.f)), 1e-12f);
          float dt = clamp1((r * eci + omr * ecj) / nrm);
          lloss += wc * (1.f - dt);
          lw += wc;
        }
      }
    }
  }

  // block reduction + global accumulate + last-block finalize
  lloss = wave_red(lloss); lw = wave_red(lw);
  if (lane == 0){ redbuf[wid] = lloss; redbuf[8 + wid] = lw; }
  __syncthreads();
  if (tid == 0){
    float tl = 0.f, tw = 0.f;
    for (int i = 0; i < NT2 / 64; ++i){ tl += redbuf[i]; tw += redbuf[8 + i]; }
    if (tl != 0.f || tw != 0.f){
      atomicAdd(&acc2[0], tl);
      atomicAdd(&acc2[1], tw);
    }
    __threadfence();
    int old = atomicAdd(done, 1);
    if (old == C_ - 1){
      float l = atomicAdd(&acc2[0], 0.f);
      float w = atomicAdd(&acc2[1], 0.f);
      out[0] = (w > 0.f) ? (l / w) : 0.f;
    }
  }
}

extern "C" void kernel_launch(void* const* d_in, const int* in_sizes, int n_in,
                              void* d_out, int out_size, void* d_ws, size_t ws_size,
                              hipStream_t stream)
{
  const float* feat   = (const float*)d_in[0];
  const float* cent   = (const float*)d_in[1];
  const int*   labels = (const int*)d_in[2];
  // d_in[3] = cam_ids: unused by the reference computation.

  char* ws = (char*)d_ws;
  float* acc2    = (float*)(ws + 0);       // 2 floats
  int*   done    = (int*)(ws + 8);         // 1 int
  int*   TP      = (int*)(ws + 12);        // 1 int
  int*   cnt     = (int*)(ws + 64);        // 128
  int*   offs    = (int*)(ws + 576);       // 128
  int*   poffs   = (int*)(ws + 1088);      // 129
  float* cnorm   = (float*)(ws + 1664);    // 128
  float* rnorm   = (float*)(ws + 2176);    // 4096
  float* rawEC   = (float*)(ws + 18560);   // 4096
  int*   members = (int*)(ws + 34944);     // 4096
  float* Sg      = (float*)(ws + 51328);   // up to SG_CAP floats

  long long avail = (long long)ws_size - 51328;
  int cap = (avail > 0) ? (int)min(avail / 4, (long long)SG_CAP) : 0;

  k_norms<<<B_ + C_ + 1, NT, 0, stream>>>(feat, cent, labels, rnorm, cnorm, rawEC,
                                          cnt, offs, poffs, TP, members, acc2, done);
  k_pairs<<<PAIR_BLOCKS, NT, 0, stream>>>(feat, rnorm, cnt, offs, poffs, TP, members, Sg, cap);
  k_select<<<C_, NT2, 0, stream>>>(feat, rnorm, cnorm, rawEC, cnt, offs, poffs,
                                   members, Sg, cap, acc2, done, (float*)d_out);
}

// Round 6
// 137.560 us; speedup vs baseline: 1.3009x; 1.3009x over previous
//
#include <hip/hip_runtime.h>

#define B_ 4096
#define C_ 128
#define D_ 768
#define NT3 512
#define NW (NT3/64)
#define M_MAX 96
#define P_MAX (M_MAX*(M_MAX-1)/2)   // 4560
#define CK 128
#define NCH (D_/CK)                 // 6
#define SROW 132
#define TILE_F (M_MAX*SROW + (M_MAX/4)*4 + 8)  // group-padded rows

__device__ __forceinline__ int rowbase(int r){ return r*SROW + (r>>2)*4; }

__device__ __forceinline__ float wave_red(float v){
#pragma unroll
  for (int o = 32; o > 0; o >>= 1) v += __shfl_down(v, o, 64);
  return v;
}
__device__ __forceinline__ float wave_min(float v){
#pragma unroll
  for (int o = 32; o > 0; o >>= 1) v = fminf(v, __shfl_down(v, o, 64));
  return v;
}
__device__ __forceinline__ float wave_max(float v){
#pragma unroll
  for (int o = 32; o > 0; o >>= 1) v = fmaxf(v, __shfl_down(v, o, 64));
  return v;
}
__device__ __forceinline__ float clamp1(float x){ return fminf(fmaxf(x, -1.f), 1.f); }
__device__ __forceinline__ unsigned rotl32(unsigned x, int r){ return (x << r) | (x >> (32 - r)); }
__device__ __forceinline__ float dot4(float4 a, float4 b){
  return fmaf(a.x, b.x, fmaf(a.y, b.y, fmaf(a.z, b.z, a.w * b.w)));
}

// jax.random.uniform(jax.random.key(1),(B,B)) element n: Threefry-2x32 key (0,1),
// counters split in halves. Bit-exact (verified rounds 1-5: absmax 0.0).
__device__ float rand_ij(unsigned n){
  const unsigned half = (unsigned)B_ * (unsigned)B_ / 2u;
  unsigned c0, c1; bool hi;
  if (n < half){ c0 = n; c1 = n + half; hi = false; }
  else         { c0 = n - half; c1 = n; hi = true; }
  const unsigned K0 = 0u, K1 = 1u, K2 = 0x1BD11BDBu;
  unsigned x0 = c0 + K0, x1 = c1 + K1;
#define TFR(r) { x0 += x1; x1 = rotl32(x1, (r)); x1 ^= x0; }
  TFR(13) TFR(15) TFR(26) TFR(6)  x0 += K1; x1 += K2 + 1u;
  TFR(17) TFR(29) TFR(16) TFR(24) x0 += K2; x1 += K0 + 2u;
  TFR(13) TFR(15) TFR(26) TFR(6)  x0 += K0; x1 += K1 + 3u;
  TFR(17) TFR(29) TFR(16) TFR(24) x0 += K1; x1 += K2 + 4u;
  TFR(13) TFR(15) TFR(26) TFR(6)  x0 += K2; x1 += K0 + 5u;
#undef TFR
  unsigned bits = hi ? x1 : x0;
  return __uint_as_float((bits >> 9) | 0x3F800000u) - 1.0f;
}

// p -> (a,b), a<b<m, row-major upper-tri. before(a) = a*(2m-1-a)/2.
__device__ __forceinline__ void decode_pair(int p, int m, int* a_, int* b_){
  float fm = (float)(2*m - 1);
  int a = (int)((fm - sqrtf(fm*fm - 8.0f*(float)p)) * 0.5f);
  a = max(0, min(a, m - 2));
  while (a > 0 && (a*(2*m - 1 - a))/2 > p) --a;
  while (((a + 1)*(2*m - 2 - a))/2 <= p) ++a;
  *a_ = a;
  *b_ = a + 1 + (p - (a*(2*m - 1 - a))/2);
}

// ---- slow-path helpers (unreachable: all classes have m<=96; insurance only) ----
__device__ float dotg(const float* x, const float* y){
  float s = 0.f;
  for (int k = 0; k < D_; ++k) s = fmaf(x[k], y[k], s);
  return s;
}
__device__ float S_pair_g(const float* feat, int ga, int gb){
  const float* ra = feat + (size_t)ga * D_;
  const float* rb = feat + (size_t)gb * D_;
  float d = dotg(ra, rb);
  float na = 1.f / fmaxf(sqrtf(dotg(ra, ra)), 1e-12f);
  float nb = 1.f / fmaxf(sqrtf(dotg(rb, rb)), 1e-12f);
  return d * na * nb;
}

// ==== single fused kernel: one block per class ====
__global__ __launch_bounds__(NT3) void k_all(
    const float* __restrict__ feat, const float* __restrict__ cent,
    const int* __restrict__ labels,
    float* __restrict__ acc2, int* __restrict__ done, float* __restrict__ out)
{
  const int c = blockIdx.x;
  const int tid = threadIdx.x;
  const int wid = tid >> 6, lane = tid & 63;

  __shared__ int   gid_s[M_MAX];
  __shared__ int   mcount;
  __shared__ __align__(16) float tile[TILE_F];
  __shared__ __align__(16) float cvec[CK];
  __shared__ __align__(16) float Sl[P_MAX];
  __shared__ __align__(16) float Pd[P_MAX];
  __shared__ unsigned short fidx_s[P_MAX];
  __shared__ float selfs[M_MAX];    // raw self-dot -> rnorm in place
  __shared__ float ecs[M_MAX];      // raw EC dot -> scaled in place
  __shared__ float cn_sh;
  __shared__ int   wcnt[NW * 64];
  __shared__ float mnb[NW], mxb[NW];
  __shared__ float lo_sh, sF_sh;
  __shared__ int   B0_sh, ex_sh, B1_sh;
  __shared__ float thr_sh;
  __shared__ float redbuf[16];

  // ---- phase A: collect members of class c (order-independent math) ----
  if (tid == 0) mcount = 0;
  __syncthreads();
  for (int i = tid; i < B_; i += NT3){
    if (labels[i] == c){
      int p = atomicAdd(&mcount, 1);
      if (p < M_MAX) gid_s[p] = i;
    }
  }
  __syncthreads();
  const int m = mcount;

  float lloss = 0.f, lw = 0.f;

  if (m >= 2 && m <= M_MAX){
    const int P = m * (m - 1) / 2;
    const int k0 = (P - 1) >> 1;
    const float wc = (float)m;
    const int G4 = (m + 3) >> 2;
    const int mpad = G4 << 2;                 // <= 96
    const int ntiles = G4 * (G4 + 1) / 2;     // <= 300

    // my 4x4 tile (row-major upper incl. diagonal)
    int ta = 0, tb = 0;
    const bool hasT = (tid < ntiles);
    if (hasT){
      int t = tid, row = 0;
      while (t >= G4 - row){ t -= G4 - row; ++row; }
      ta = row; tb = row + t;
    }
    float acc[16];
#pragma unroll
    for (int i = 0; i < 16; ++i) acc[i] = 0.f;
    float selfacc = 0.f, ecacc = 0.f, cacc = 0.f;
    const int stid = tid - (NT3 - M_MAX);     // [0,96) for tids 416..511

    // ---- phase B: chunked staging + register-tiled raw Gram + self/EC dots ----
    for (int ch = 0; ch < NCH; ++ch){
      const int d0 = ch * CK;
      __syncthreads();      // previous chunk's readers done
      {
        const float4 z4 = make_float4(0.f, 0.f, 0.f, 0.f);
        for (int e = tid; e < mpad * (CK / 4); e += NT3){
          int r = e >> 5, j = e & 31;
          float4 v = z4;
          if (r < m) v = ((const float4*)(feat + (size_t)gid_s[r] * D_ + d0))[j];
          ((float4*)&tile[rowbase(r)])[j] = v;
        }
        if (tid < CK / 4)
          ((float4*)cvec)[tid] = ((const float4*)(cent + (size_t)c * D_ + d0))[tid];
      }
      __syncthreads();
      if (hasT){
        const float4* A0 = (const float4*)&tile[rowbase(4*ta + 0)];
        const float4* A1 = (const float4*)&tile[rowbase(4*ta + 1)];
        const float4* A2 = (const float4*)&tile[rowbase(4*ta + 2)];
        const float4* A3 = (const float4*)&tile[rowbase(4*ta + 3)];
        const float4* B0 = (const float4*)&tile[rowbase(4*tb + 0)];
        const float4* B1 = (const float4*)&tile[rowbase(4*tb + 1)];
        const float4* B2 = (const float4*)&tile[rowbase(4*tb + 2)];
        const float4* B3 = (const float4*)&tile[rowbase(4*tb + 3)];
#pragma unroll 4
        for (int j = 0; j < CK / 4; ++j){
          float4 a0 = A0[j], a1 = A1[j], a2 = A2[j], a3 = A3[j];
          float4 b0 = B0[j], b1 = B1[j], b2 = B2[j], b3 = B3[j];
          acc[ 0] += dot4(a0, b0); acc[ 1] += dot4(a0, b1);
          acc[ 2] += dot4(a0, b2); acc[ 3] += dot4(a0, b3);
          acc[ 4] += dot4(a1, b0); acc[ 5] += dot4(a1, b1);
          acc[ 6] += dot4(a1, b2); acc[ 7] += dot4(a1, b3);
          acc[ 8] += dot4(a2, b0); acc[ 9] += dot4(a2, b1);
          acc[10] += dot4(a2, b2); acc[11] += dot4(a2, b3);
          acc[12] += dot4(a3, b0); acc[13] += dot4(a3, b1);
          acc[14] += dot4(a3, b2); acc[15] += dot4(a3, b3);
        }
      }
      if (stid >= 0 && stid < m){             // tids 416.. : self + EC raw dots
        const float4* R  = (const float4*)&tile[rowbase(stid)];
        const float4* Cv = (const float4*)cvec;
#pragma unroll 4
        for (int j = 0; j < CK / 4; ++j){
          float4 v = R[j], w = Cv[j];
          selfacc += dot4(v, v);
          ecacc   += dot4(v, w);
        }
      }
      if (wid == 5){                          // tids 320..383: center sumsq
        float v1 = cvec[lane], v2 = cvec[lane + 64];
        cacc = fmaf(v1, v1, fmaf(v2, v2, cacc));
      }
    }
    __syncthreads();
    if (stid >= 0 && stid < m){ selfs[stid] = selfacc; ecs[stid] = ecacc; }
    if (wid == 5){ float t = wave_red(cacc); if (lane == 0) cn_sh = t; }
    __syncthreads();
    if (tid < m){
      float rn  = 1.f / fmaxf(sqrtf(selfs[tid]), 1e-12f);
      float cno = 1.f / fmaxf(sqrtf(cn_sh), 1e-12f);
      selfs[tid] = rn;
      ecs[tid] = ecs[tid] * rn * cno;
    }
    __syncthreads();

    // ---- phase C: scatter S/pd into pair order, track min/max of pd ----
    float pmn = 1e30f, pmx = -1e30f;
    if (hasT){
#pragma unroll
      for (int ai = 0; ai < 4; ++ai){
#pragma unroll
        for (int bi = 0; bi < 4; ++bi){
          int a = 4*ta + ai, b = 4*tb + bi;
          if (a < b && b < m){
            float S = acc[ai*4 + bi] * selfs[a] * selfs[b];
            float pd = 1.f - clamp1(S);
            int p = (a*(2*m - 1 - a))/2 + (b - a - 1);
            Sl[p] = S; Pd[p] = pd;
            pmn = fminf(pmn, pd); pmx = fmaxf(pmx, pd);
          }
        }
      }
    }
    pmn = wave_min(pmn); pmx = wave_max(pmx);
    if (lane == 0){ mnb[wid] = pmn; mxb[wid] = pmx; }
    __syncthreads();
    if (tid == 0){
      float mn = mnb[0], mx = mxb[0];
#pragma unroll
      for (int i = 1; i < NW; ++i){ mn = fminf(mn, mnb[i]); mx = fmaxf(mx, mxb[i]); }
      lo_sh = mn;
      sF_sh = 4096.f / fmaxf(mx - mn, 1e-20f);
    }
    __syncthreads();
    const float lo = lo_sh, sF = sF_sh;

    // ---- phase D: two-level ballot rank-select (4096 fine buckets) ----
    const int nch = (P + NT3 - 1) / NT3;
    int cl = 0;
    for (int t = 0; t < nch; ++t){
      int p = tid + t * NT3;
      int bkt = -1;
      if (p < P){
        int f = (int)((Pd[p] - lo) * sF);
        f = max(0, min(4095, f));
        fidx_s[p] = (unsigned short)f;
        bkt = f >> 6;
      }
#pragma unroll
      for (int k = 0; k < 64; ++k){
        unsigned long long msk = __ballot(bkt == k);
        if (lane == k) cl += __popcll(msk);
      }
    }
    wcnt[wid*64 + lane] = cl;
    __syncthreads();
    if (tid < 64){
      int tot = 0;
#pragma unroll
      for (int w = 0; w < NW; ++w) tot += wcnt[w*64 + tid];
      int inc = tot;
#pragma unroll
      for (int o = 1; o < 64; o <<= 1){
        int v = __shfl_up(inc, o, 64);
        if (tid >= o) inc += v;
      }
      int excl = inc - tot;
      if (excl <= k0 && k0 < inc){ B0_sh = tid; ex_sh = excl; }
    }
    __syncthreads();
    const int Bsel0 = B0_sh;
    const int kt = k0 - ex_sh;          // target rank within coarse bucket
    cl = 0;
    for (int t = 0; t < nch; ++t){
      int p = tid + t * NT3;
      int bkt = -1;
      if (p < P){
        int f = fidx_s[p];
        if ((f >> 6) == Bsel0) bkt = f & 63;
      }
#pragma unroll
      for (int k = 0; k < 64; ++k){
        unsigned long long msk = __ballot(bkt == k);
        if (lane == k) cl += __popcll(msk);
      }
    }
    wcnt[wid*64 + lane] = cl;
    __syncthreads();
    if (tid < 64){
      int tot = 0;
#pragma unroll
      for (int w = 0; w < NW; ++w) tot += wcnt[w*64 + tid];
      int inc = tot;
#pragma unroll
      for (int o = 1; o < 64; o <<= 1){
        int v = __shfl_up(inc, o, 64);
        if (tid >= o) inc += v;
      }
      int excl = inc - tot;
      if (excl <= kt && kt < inc) B1_sh = tid;
    }
    __syncthreads();
    const int fsel = (Bsel0 << 6) | B1_sh;

    // exact recount for the ~1-2 candidates in the fine bucket (bit-exact thr)
    {
      const float4* Pd4 = (const float4*)Pd;
      const int nq4 = P >> 2;
      for (int p = tid; p < P; p += NT3){
        if (fidx_s[p] == (unsigned short)fsel){
          const float pdp = Pd[p];
          int lt = 0, eq = 0;
#pragma unroll 4
          for (int q4 = 0; q4 < nq4; ++q4){
            float4 v = Pd4[q4];
            lt += (v.x < pdp) + (v.y < pdp) + (v.z < pdp) + (v.w < pdp);
            eq += (v.x == pdp) + (v.y == pdp) + (v.z == pdp) + (v.w == pdp);
          }
          for (int q = nq4 << 2; q < P; ++q){
            float pdq = Pd[q];
            lt += (pdq < pdp); eq += (pdq == pdp);
          }
          if (lt <= k0 && k0 < lt + eq) thr_sh = pdp;
        }
      }
    }
    __syncthreads();
    const float thr = thr_sh;

    // ---- phase E: loss over selected pairs ----
    for (int p = tid; p < P; p += NT3){
      float pd = Pd[p];
      if (pd > thr){
        float S = Sl[p];
        int a, b; decode_pair(p, m, &a, &b);
        int ga = gid_s[a], gb = gid_s[b];
        float ea = ecs[a], eb = ecs[b];
        int i, j; float eci, ecj;
        if (ga < gb){ i = ga; j = gb; eci = ea; ecj = eb; }
        else        { i = gb; j = ga; eci = eb; ecj = ea; }
        float r = rand_ij((unsigned)i * (unsigned)B_ + (unsigned)j);
        float omr = 1.f - r;
        float n2 = r * r + omr * omr + 2.f * r * omr * S;    // raw (unclipped) S
        float nrm = fmaxf(sqrtf(fmaxf(n2, 0.f)), 1e-12f);
        float dt = clamp1((r * eci + omr * ecj) / nrm);
        lloss += wc * (1.f - dt);
        lw += wc;
      }
    }
  } else if (m > M_MAX){
    // correctness-only fallback (impossible here: all m<=96, verified R1-R5)
    int* mem = (int*)Sl;                       // m <= 4096 <= P_MAX
    if (tid == 0) B0_sh = 0;
    __syncthreads();
    for (int i = tid; i < B_; i += NT3)
      if (labels[i] == c){ int p = atomicAdd(&B0_sh, 1); mem[p] = i; }
    __syncthreads();
    const int P = m * (m - 1) / 2;
    const int k0 = (P - 1) >> 1;
    const float wc = (float)m;
    const float* cc = cent + (size_t)c * D_;
    const float cno = 1.f / fmaxf(sqrtf(dotg(cc, cc)), 1e-12f);
    for (int p = tid; p < P; p += NT3){
      int a, b; decode_pair(p, m, &a, &b);
      float pdp = 1.f - clamp1(S_pair_g(feat, mem[a], mem[b]));
      int lt = 0, eq = 0;
      for (int q = 0; q < P; ++q){
        int a2, b2; decode_pair(q, m, &a2, &b2);
        float pdq = 1.f - clamp1(S_pair_g(feat, mem[a2], mem[b2]));
        lt += (pdq < pdp); eq += (pdq == pdp);
      }
      if (lt <= k0 && k0 < lt + eq) thr_sh = pdp;
    }
    __syncthreads();
    const float thr = thr_sh;
    for (int p = tid; p < P; p += NT3){
      int a, b; decode_pair(p, m, &a, &b);
      int ga = mem[a], gb = mem[b];
      float S = S_pair_g(feat, ga, gb);
      float pd = 1.f - clamp1(S);
      if (pd > thr){
        if (ga > gb){ int t2 = ga; ga = gb; gb = t2; }
        const float* ra = feat + (size_t)ga * D_;
        const float* rb = feat + (size_t)gb * D_;
        float eci = dotg(ra, cc) / fmaxf(sqrtf(dotg(ra, ra)), 1e-12f) * cno;
        float ecj = dotg(rb, cc) / fmaxf(sqrtf(dotg(rb, rb)), 1e-12f) * cno;
        float r = rand_ij((unsigned)ga * (unsigned)B_ + (unsigned)gb);
        float omr = 1.f - r;
        float n2 = r * r + omr * omr + 2.f * r * omr * S;
        float nrm = fmaxf(sqrtf(fmaxf(n2, 0.f)), 1e-12f);
        float dt = clamp1((r * eci + omr * ecj) / nrm);
        lloss += wc * (1.f - dt);
        lw += wc;
      }
    }
  }
  // m < 2: nothing to add

  // ---- phase F: block reduce + device accumulate + last-block finalize ----
  lloss = wave_red(lloss); lw = wave_red(lw);
  if (lane == 0){ redbuf[wid] = lloss; redbuf[8 + wid] = lw; }
  __syncthreads();
  if (tid == 0){
    float tl = 0.f, tw = 0.f;
#pragma unroll
    for (int i = 0; i < NW; ++i){ tl += redbuf[i]; tw += redbuf[8 + i]; }
    if (tl != 0.f || tw != 0.f){
      atomicAdd(&acc2[0], tl);
      atomicAdd(&acc2[1], tw);
    }
    __threadfence();
    int old = atomicAdd(done, 1);
    if (old == C_ - 1){
      float l = atomicAdd(&acc2[0], 0.f);
      float w = atomicAdd(&acc2[1], 0.f);
      out[0] = (w > 0.f) ? (l / w) : 0.f;
    }
  }
}

extern "C" void kernel_launch(void* const* d_in, const int* in_sizes, int n_in,
                              void* d_out, int out_size, void* d_ws, size_t ws_size,
                              hipStream_t stream)
{
  const float* feat   = (const float*)d_in[0];
  const float* cent   = (const float*)d_in[1];
  const int*   labels = (const int*)d_in[2];
  // d_in[3] = cam_ids: unused by the reference computation.

  char* ws = (char*)d_ws;
  float* acc2 = (float*)(ws + 0);   // loss, wsum
  int*   done = (int*)(ws + 8);

  hipMemsetAsync(ws, 0, 16, stream);
  k_all<<<C_, NT3, 0, stream>>>(feat, cent, labels, acc2, done, (float*)d_out);
}

// Round 7
// 133.418 us; speedup vs baseline: 1.3412x; 1.0310x over previous
//
#include <hip/hip_runtime.h>

#define B_ 4096
#define C_ 128
#define D_ 768
#define NT 512
#define NW (NT/64)
#define M_MAX 96
#define P_MAX (M_MAX*(M_MAX-1)/2)   // 4560
#define CK 128
#define NCH (D_/CK)                 // 6
#define SROW 132                    // 2-way-only LDS aliasing for row-stride reads
#define RC 127                      // row code meaning "cvec"
#define NIDX_MAX (P_MAX + 2*M_MAX + 1)      // 4753
#define PPT ((NIDX_MAX + NT - 1)/NT)        // 10

__device__ __forceinline__ float wave_red(float v){
#pragma unroll
  for (int o = 32; o > 0; o >>= 1) v += __shfl_down(v, o, 64);
  return v;
}
__device__ __forceinline__ float wave_min(float v){
#pragma unroll
  for (int o = 32; o > 0; o >>= 1) v = fminf(v, __shfl_down(v, o, 64));
  return v;
}
__device__ __forceinline__ float wave_max(float v){
#pragma unroll
  for (int o = 32; o > 0; o >>= 1) v = fmaxf(v, __shfl_down(v, o, 64));
  return v;
}
__device__ __forceinline__ float clamp1(float x){ return fminf(fmaxf(x, -1.f), 1.f); }
__device__ __forceinline__ unsigned rotl32(unsigned x, int r){ return (x << r) | (x >> (32 - r)); }
__device__ __forceinline__ float dot4(float4 a, float4 b){
  return fmaf(a.x, b.x, fmaf(a.y, b.y, fmaf(a.z, b.z, a.w * b.w)));
}

// jax.random.uniform(jax.random.key(1),(B,B)) element n: Threefry-2x32 key (0,1),
// counters split in halves. Bit-exact (verified rounds 1-6: absmax 0.0).
__device__ float rand_ij(unsigned n){
  const unsigned half = (unsigned)B_ * (unsigned)B_ / 2u;
  unsigned c0, c1; bool hi;
  if (n < half){ c0 = n; c1 = n + half; hi = false; }
  else         { c0 = n - half; c1 = n; hi = true; }
  const unsigned K0 = 0u, K1 = 1u, K2 = 0x1BD11BDBu;
  unsigned x0 = c0 + K0, x1 = c1 + K1;
#define TFR(r) { x0 += x1; x1 = rotl32(x1, (r)); x1 ^= x0; }
  TFR(13) TFR(15) TFR(26) TFR(6)  x0 += K1; x1 += K2 + 1u;
  TFR(17) TFR(29) TFR(16) TFR(24) x0 += K2; x1 += K0 + 2u;
  TFR(13) TFR(15) TFR(26) TFR(6)  x0 += K0; x1 += K1 + 3u;
  TFR(17) TFR(29) TFR(16) TFR(24) x0 += K1; x1 += K2 + 4u;
  TFR(13) TFR(15) TFR(26) TFR(6)  x0 += K2; x1 += K0 + 5u;
#undef TFR
  unsigned bits = hi ? x1 : x0;
  return __uint_as_float((bits >> 9) | 0x3F800000u) - 1.0f;
}

// p -> (a,b), a<b<m, row-major upper-tri. before(a) = a*(2m-1-a)/2.
__device__ __forceinline__ void decode_pair(int p, int m, int* a_, int* b_){
  float fm = (float)(2*m - 1);
  int a = (int)((fm - sqrtf(fm*fm - 8.0f*(float)p)) * 0.5f);
  a = max(0, min(a, m - 2));
  while (a > 0 && (a*(2*m - 1 - a))/2 > p) --a;
  while (((a + 1)*(2*m - 2 - a))/2 <= p) ++a;
  *a_ = a;
  *b_ = a + 1 + (p - (a*(2*m - 1 - a))/2);
}

// ---- slow-path helpers (unreachable: all classes have m<=96; insurance only) ----
__device__ float dotg(const float* x, const float* y){
  float s = 0.f;
  for (int k = 0; k < D_; ++k) s = fmaf(x[k], y[k], s);
  return s;
}
__device__ float S_pair_g(const float* feat, int ga, int gb){
  const float* ra = feat + (size_t)ga * D_;
  const float* rb = feat + (size_t)gb * D_;
  float d = dotg(ra, rb);
  float na = 1.f / fmaxf(sqrtf(dotg(ra, ra)), 1e-12f);
  float nb = 1.f / fmaxf(sqrtf(dotg(rb, rb)), 1e-12f);
  return d * na * nb;
}

// ==== single fused kernel: one block per class ====
__global__ __launch_bounds__(NT) void k_all(
    const float* __restrict__ feat, const float* __restrict__ cent,
    const int* __restrict__ labels,
    float* __restrict__ acc2, int* __restrict__ done, float* __restrict__ out)
{
  const int c = blockIdx.x;
  const int tid = threadIdx.x;
  const int wid = tid >> 6, lane = tid & 63;

  __shared__ int   gid_s[M_MAX];
  __shared__ int   mcount;
  __shared__ __align__(16) float tile[M_MAX * SROW];   // 50688 B
  __shared__ __align__(16) float cvec[CK];
  __shared__ __align__(16) float Sl[P_MAX];
  __shared__ __align__(16) float Pd[P_MAX];
  __shared__ unsigned short fidx_s[P_MAX];
  __shared__ float selfs[M_MAX];    // raw self-dot -> rnorm in place
  __shared__ float ecs[M_MAX];      // raw EC dot -> scaled in place
  __shared__ float cn_sh;           // raw center self-dot
  __shared__ int   wcnt[NW * 64];
  __shared__ float mnb[NW], mxb[NW];
  __shared__ float lo_sh, sF_sh;
  __shared__ int   B0_sh, ex_sh, B1_sh;
  __shared__ float thr_sh;
  __shared__ float redbuf[16];

  // ---- phase A: collect members of class c (order-independent math) ----
  if (tid == 0) mcount = 0;
  __syncthreads();
  for (int i = tid; i < B_; i += NT){
    if (labels[i] == c){
      int p = atomicAdd(&mcount, 1);
      if (p < M_MAX) gid_s[p] = i;
    }
  }
  __syncthreads();
  const int m = mcount;

  float lloss = 0.f, lw = 0.f;

  if (m >= 2 && m <= M_MAX){
    const int P = m * (m - 1) / 2;
    const int k0 = (P - 1) >> 1;
    const float wc = (float)m;

    // ---- slot setup: one index per dot product ----
    // idx < P:            pair (a,b)
    // idx < P+m:          self-dot of row idx-P
    // idx < P+2m:         EC dot (row idx-P-m) . cvec
    // idx == P+2m:        cvec . cvec
    const int NIDX = P + 2*m + 1;
    int   nsl = 0;
    int   meta[PPT];      // (p2<<14) | (ra<<7) | rb   (RC=127 means cvec)
    float acc[PPT];
#pragma unroll
    for (int t = 0; t < PPT; ++t){ acc[t] = 0.f; meta[t] = 0; }
    for (int idx = tid; idx < NIDX; idx += NT){
      int ra, rb;
      if (idx < P){ decode_pair(idx, m, &ra, &rb); }
      else if (idx < P + m){ ra = rb = idx - P; }
      else if (idx < P + 2*m){ ra = idx - P - m; rb = RC; }
      else { ra = RC; rb = RC; }
      meta[nsl++] = (idx << 14) | (ra << 7) | rb;
    }

    // ---- phase B: chunked staging + thread-per-dot Gram ----
    for (int ch = 0; ch < NCH; ++ch){
      const int d0 = ch * CK;
      __syncthreads();      // previous chunk's readers done
      for (int e = tid; e < m * (CK/4); e += NT){
        int r = e >> 5, j = e & 31;
        ((float4*)&tile[r * SROW])[j] =
            ((const float4*)(feat + (size_t)gid_s[r] * D_ + d0))[j];
      }
      if (tid < CK/4)
        ((float4*)cvec)[tid] = ((const float4*)(cent + (size_t)c * D_ + d0))[tid];
      __syncthreads();
#pragma unroll
      for (int t = 0; t < PPT; ++t){
        if (t < nsl){
          const int mt = meta[t];
          const int ra = (mt >> 7) & 127, rb = mt & 127;
          const float4* A = (ra == RC) ? (const float4*)cvec : (const float4*)&tile[ra * SROW];
          const float4* Bp = (rb == RC) ? (const float4*)cvec : (const float4*)&tile[rb * SROW];
          float s = 0.f;
#pragma unroll 8
          for (int j = 0; j < CK/4; ++j) s += dot4(A[j], Bp[j]);
          acc[t] += s;
        }
      }
    }
    __syncthreads();        // tile readers done (Sl does not alias tile, but keep order)

    // ---- combine: single owner-writes pass of raw dots ----
#pragma unroll
    for (int t = 0; t < PPT; ++t){
      if (t < nsl){
        const int p2 = meta[t] >> 14;
        const float v = acc[t];
        if (p2 < P) Sl[p2] = v;
        else if (p2 < P + m) selfs[p2 - P] = v;
        else if (p2 < P + 2*m) ecs[p2 - P - m] = v;
        else cn_sh = v;
      }
    }
    __syncthreads();
    if (tid < m){
      float rn  = 1.f / fmaxf(sqrtf(selfs[tid]), 1e-12f);
      float cno = 1.f / fmaxf(sqrtf(cn_sh), 1e-12f);
      selfs[tid] = rn;
      ecs[tid] = ecs[tid] * rn * cno;
    }
    __syncthreads();

    // ---- phase C: normalize pairs, compute pd, track min/max ----
    float pmn = 1e30f, pmx = -1e30f;
    for (int p = tid; p < P; p += NT){
      int a, b; decode_pair(p, m, &a, &b);
      float S = Sl[p] * selfs[a] * selfs[b];
      float pd = 1.f - clamp1(S);
      Sl[p] = S; Pd[p] = pd;
      pmn = fminf(pmn, pd); pmx = fmaxf(pmx, pd);
    }
    pmn = wave_min(pmn); pmx = wave_max(pmx);
    if (lane == 0){ mnb[wid] = pmn; mxb[wid] = pmx; }
    __syncthreads();
    if (tid == 0){
      float mn = mnb[0], mx = mxb[0];
#pragma unroll
      for (int i = 1; i < NW; ++i){ mn = fminf(mn, mnb[i]); mx = fmaxf(mx, mxb[i]); }
      lo_sh = mn;
      sF_sh = 4096.f / fmaxf(mx - mn, 1e-20f);
    }
    __syncthreads();
    const float lo = lo_sh, sF = sF_sh;

    // ---- phase D: two-level ballot rank-select (4096 fine buckets) ----
    const int nch = (P + NT - 1) / NT;
    int cl = 0;
    for (int t = 0; t < nch; ++t){
      int p = tid + t * NT;
      int bkt = -1;
      if (p < P){
        int f = (int)((Pd[p] - lo) * sF);
        f = max(0, min(4095, f));
        fidx_s[p] = (unsigned short)f;
        bkt = f >> 6;
      }
#pragma unroll
      for (int k = 0; k < 64; ++k){
        unsigned long long msk = __ballot(bkt == k);
        if (lane == k) cl += __popcll(msk);
      }
    }
    wcnt[wid*64 + lane] = cl;
    __syncthreads();
    if (tid < 64){
      int tot = 0;
#pragma unroll
      for (int w = 0; w < NW; ++w) tot += wcnt[w*64 + tid];
      int inc = tot;
#pragma unroll
      for (int o = 1; o < 64; o <<= 1){
        int v = __shfl_up(inc, o, 64);
        if (tid >= o) inc += v;
      }
      int excl = inc - tot;
      if (excl <= k0 && k0 < inc){ B0_sh = tid; ex_sh = excl; }
    }
    __syncthreads();
    const int Bsel0 = B0_sh;
    const int kt = k0 - ex_sh;
    cl = 0;
    for (int t = 0; t < nch; ++t){
      int p = tid + t * NT;
      int bkt = -1;
      if (p < P){
        int f = fidx_s[p];
        if ((f >> 6) == Bsel0) bkt = f & 63;
      }
#pragma unroll
      for (int k = 0; k < 64; ++k){
        unsigned long long msk = __ballot(bkt == k);
        if (lane == k) cl += __popcll(msk);
      }
    }
    wcnt[wid*64 + lane] = cl;
    __syncthreads();
    if (tid < 64){
      int tot = 0;
#pragma unroll
      for (int w = 0; w < NW; ++w) tot += wcnt[w*64 + tid];
      int inc = tot;
#pragma unroll
      for (int o = 1; o < 64; o <<= 1){
        int v = __shfl_up(inc, o, 64);
        if (tid >= o) inc += v;
      }
      int excl = inc - tot;
      if (excl <= kt && kt < inc) B1_sh = tid;
    }
    __syncthreads();
    const int fsel = (Bsel0 << 6) | B1_sh;

    // exact recount for the ~1-2 candidates in the fine bucket (bit-exact thr)
    {
      const float4* Pd4 = (const float4*)Pd;
      const int nq4 = P >> 2;
      for (int p = tid; p < P; p += NT){
        if (fidx_s[p] == (unsigned short)fsel){
          const float pdp = Pd[p];
          int lt = 0, eq = 0;
#pragma unroll 4
          for (int q4 = 0; q4 < nq4; ++q4){
            float4 v = Pd4[q4];
            lt += (v.x < pdp) + (v.y < pdp) + (v.z < pdp) + (v.w < pdp);
            eq += (v.x == pdp) + (v.y == pdp) + (v.z == pdp) + (v.w == pdp);
          }
          for (int q = nq4 << 2; q < P; ++q){
            float pdq = Pd[q];
            lt += (pdq < pdp); eq += (pdq == pdp);
          }
          if (lt <= k0 && k0 < lt + eq) thr_sh = pdp;
        }
      }
    }
    __syncthreads();
    const float thr = thr_sh;

    // ---- phase E: loss over selected pairs ----
    for (int p = tid; p < P; p += NT){
      float pd = Pd[p];
      if (pd > thr){
        float S = Sl[p];
        int a, b; decode_pair(p, m, &a, &b);
        int ga = gid_s[a], gb = gid_s[b];
        float ea = ecs[a], eb = ecs[b];
        int i, j; float eci, ecj;
        if (ga < gb){ i = ga; j = gb; eci = ea; ecj = eb; }
        else        { i = gb; j = ga; eci = eb; ecj = ea; }
        float r = rand_ij((unsigned)i * (unsigned)B_ + (unsigned)j);
        float omr = 1.f - r;
        float n2 = r * r + omr * omr + 2.f * r * omr * S;    // raw (unclipped) S
        float nrm = fmaxf(sqrtf(fmaxf(n2, 0.f)), 1e-12f);
        float dt = clamp1((r * eci + omr * ecj) / nrm);
        lloss += wc * (1.f - dt);
        lw += wc;
      }
    }
  } else if (m > M_MAX){
    // correctness-only fallback (impossible here: all m<=96, verified R1-R6)
    int* mem = (int*)Sl;                       // m <= 4096 <= P_MAX
    if (tid == 0) B0_sh = 0;
    __syncthreads();
    for (int i = tid; i < B_; i += NT)
      if (labels[i] == c){ int p = atomicAdd(&B0_sh, 1); mem[p] = i; }
    __syncthreads();
    const int P = m * (m - 1) / 2;
    const int k0 = (P - 1) >> 1;
    const float wc = (float)m;
    const float* cc = cent + (size_t)c * D_;
    const float cno = 1.f / fmaxf(sqrtf(dotg(cc, cc)), 1e-12f);
    for (int p = tid; p < P; p += NT){
      int a, b; decode_pair(p, m, &a, &b);
      float pdp = 1.f - clamp1(S_pair_g(feat, mem[a], mem[b]));
      int lt = 0, eq = 0;
      for (int q = 0; q < P; ++q){
        int a2, b2; decode_pair(q, m, &a2, &b2);
        float pdq = 1.f - clamp1(S_pair_g(feat, mem[a2], mem[b2]));
        lt += (pdq < pdp); eq += (pdq == pdp);
      }
      if (lt <= k0 && k0 < lt + eq) thr_sh = pdp;
    }
    __syncthreads();
    const float thr = thr_sh;
    for (int p = tid; p < P; p += NT){
      int a, b; decode_pair(p, m, &a, &b);
      int ga = mem[a], gb = mem[b];
      float S = S_pair_g(feat, ga, gb);
      float pd = 1.f - clamp1(S);
      if (pd > thr){
        if (ga > gb){ int t2 = ga; ga = gb; gb = t2; }
        const float* ra = feat + (size_t)ga * D_;
        const float* rb = feat + (size_t)gb * D_;
        float eci = dotg(ra, cc) / fmaxf(sqrtf(dotg(ra, ra)), 1e-12f) * cno;
        float ecj = dotg(rb, cc) / fmaxf(sqrtf(dotg(rb, rb)), 1e-12f) * cno;
        float r = rand_ij((unsigned)ga * (unsigned)B_ + (unsigned)gb);
        float omr = 1.f - r;
        float n2 = r * r + omr * omr + 2.f * r * omr * S;
        float nrm = fmaxf(sqrtf(fmaxf(n2, 0.f)), 1e-12f);
        float dt = clamp1((r * eci + omr * ecj) / nrm);
        lloss += wc * (1.f - dt);
        lw += wc;
      }
    }
  }
  // m < 2: nothing to add

  // ---- phase F: block reduce + device accumulate + last-block finalize ----
  lloss = wave_red(lloss); lw = wave_red(lw);
  if (lane == 0){ redbuf[wid] = lloss; redbuf[8 + wid] = lw; }
  __syncthreads();
  if (tid == 0){
    float tl = 0.f, tw = 0.f;
#pragma unroll
    for (int i = 0; i < NW; ++i){ tl += redbuf[i]; tw += redbuf[8 + i]; }
    if (tl != 0.f || tw != 0.f){
      atomicAdd(&acc2[0], tl);
      atomicAdd(&acc2[1], tw);
    }
    __threadfence();
    int old = atomicAdd(done, 1);
    if (old == C_ - 1){
      float l = atomicAdd(&acc2[0], 0.f);
      float w = atomicAdd(&acc2[1], 0.f);
      out[0] = (w > 0.f) ? (l / w) : 0.f;
    }
  }
}

extern "C" void kernel_launch(void* const* d_in, const int* in_sizes, int n_in,
                              void* d_out, int out_size, void* d_ws, size_t ws_size,
                              hipStream_t stream)
{
  const float* feat   = (const float*)d_in[0];
  const float* cent   = (const float*)d_in[1];
  const int*   labels = (const int*)d_in[2];
  // d_in[3] = cam_ids: unused by the reference computation.

  char* ws = (char*)d_ws;
  float* acc2 = (float*)(ws + 0);   // loss, wsum
  int*   done = (int*)(ws + 8);

  hipMemsetAsync(ws, 0, 16, stream);
  k_all<<<C_, NT, 0, stream>>>(feat, cent, labels, acc2, done, (float*)d_out);
}